// Round 12
// baseline (7173.310 us; speedup 1.0000x reference)
//
#include <hip/hip_runtime.h>

// ---------------------------------------------------------------------------
// LSTMPPOPolicy: encoder(2x Linear+SiLU) -> LSTM(T=512 scan) -> LN -> heads
// B=32 T=512 OBS=256 ENC=1024 H=1024 A=64.  fp16 MFMA (f32 accum).
// R12: R10 skeleton + tagged-slot speculation with SOUND bounded fallback.
// h exchanged as {h-pair, tag} 8B slots; consumer issues payload read with
// NO prior poll, validates tags (hit => detect leg merged into data load);
// on miss: R10 per-wave flag poll + ONE re-read (no unbounded retry storm).
// Producers publish per-wave flags after vmcnt drain every step (fallback).
// R11's gx fusion reverted (regressed: pre-poll work adds to cycle time).
// ---------------------------------------------------------------------------

typedef _Float16 half8 __attribute__((ext_vector_type(8)));
typedef _Float16 half4v __attribute__((ext_vector_type(4)));
typedef float floatx4 __attribute__((ext_vector_type(4)));
typedef unsigned long long ull;

__device__ __forceinline__ float sigmoidf_(float x) { return 1.f / (1.f + __expf(-x)); }
__device__ __forceinline__ float tanhf_(float x) {
  x = fminf(15.f, fmaxf(-15.f, x));
  float e = __expf(-2.f * x);
  return (1.f - e) / (1.f + e);
}

// ---------------- merged f32 -> f16 convert (7 segments, grid-stride) ------
__global__ __launch_bounds__(256) void k_convert_all(
    const float* s0, _Float16* d0, int n0,   // vec4 counts
    const float* s1, _Float16* d1, int n1,
    const float* s2, _Float16* d2, int n2,
    const float* s3, _Float16* d3, int n3,
    const float* s4, _Float16* d4, int n4,
    const float* s5, _Float16* d5, int n5,
    const float* s6, _Float16* d6, int n6)
{
  const int gid = blockIdx.x * 256 + threadIdx.x;
  const int stride = gridDim.x * 256;
#define CONV_SEG(s, d, n)                                                  \
  for (int i = gid; i < (n); i += stride) {                                \
    floatx4 v = *(const floatx4*)((s) + (size_t)i * 4);                    \
    half4v h;                                                              \
    h[0] = (_Float16)v[0]; h[1] = (_Float16)v[1];                          \
    h[2] = (_Float16)v[2]; h[3] = (_Float16)v[3];                          \
    *(half4v*)((d) + (size_t)i * 4) = h;                                   \
  }
  CONV_SEG(s0, d0, n0)
  CONV_SEG(s1, d1, n1)
  CONV_SEG(s2, d2, n2)
  CONV_SEG(s3, d3, n3)
  CONV_SEG(s4, d4, n4)
  CONV_SEG(s5, d5, n5)
  CONV_SEG(s6, d6, n6)
#undef CONV_SEG
}

// ---------------- tagged h_0 init: hT[0][batch][pair] = {h0,h1,tag=1} ------
__global__ __launch_bounds__(256) void k_inith(const float* __restrict__ hxs,
                                               ull* __restrict__ hT) {
  int s = blockIdx.x * 256 + threadIdx.x;      // 0..16383
  int batch = s >> 9, pair = s & 511;
  union { _Float16 h[2]; unsigned u; } p;
  p.h[0] = (_Float16)hxs[batch * 1024 + pair * 2];
  p.h[1] = (_Float16)hxs[batch * 1024 + pair * 2 + 1];
  hT[s] = (ull)p.u | (1ull << 32);
}

// ---------------- fp16 MFMA GEMM: C = epi(A @ B^T + bias) ------------------
template<int EPI>
__global__ __launch_bounds__(256) void k_gemm(
    const _Float16* __restrict__ A, const _Float16* __restrict__ B,
    _Float16* __restrict__ C, const float* __restrict__ bias0,
    const float* __restrict__ bias1, int M, int N, int K)
{
  __shared__ _Float16 As[128 * 32];
  __shared__ _Float16 Bs[128 * 32];
  const int tid = threadIdx.x;
  const int l = tid & 63;
  const int w = tid >> 6;
  const int wr = w >> 1, wc = w & 1;
  const _Float16* Ab = A + (size_t)blockIdx.x * 128 * K;
  const _Float16* Bb = B + (size_t)blockIdx.y * 128 * K;

  floatx4 acc[4][4];
#pragma unroll
  for (int a = 0; a < 4; ++a)
#pragma unroll
    for (int b = 0; b < 4; ++b) acc[a][b] = (floatx4){0.f, 0.f, 0.f, 0.f};

  const int ci0 = tid, ci1 = tid + 256;
  const int r0 = ci0 >> 2, r1 = ci1 >> 2;
  const int q0 = (ci0 & 3) ^ ((r0 >> 2) & 3);
  const int q1 = (ci1 & 3) ^ ((r1 >> 2) & 3);
  const int lr = l & 15;
  const int ko = l >> 4;
  const int nkt = K >> 5;

  for (int kt = 0; kt < nkt; ++kt) {
    const _Float16* Ak = Ab + kt * 32;
    const _Float16* Bk = Bb + kt * 32;
    uint4 va0 = *(const uint4*)(Ak + (size_t)r0 * K + q0 * 8);
    uint4 va1 = *(const uint4*)(Ak + (size_t)r1 * K + q1 * 8);
    uint4 vb0 = *(const uint4*)(Bk + (size_t)r0 * K + q0 * 8);
    uint4 vb1 = *(const uint4*)(Bk + (size_t)r1 * K + q1 * 8);
    __syncthreads();
    *(uint4*)(As + ci0 * 8) = va0;
    *(uint4*)(As + ci1 * 8) = va1;
    *(uint4*)(Bs + ci0 * 8) = vb0;
    *(uint4*)(Bs + ci1 * 8) = vb1;
    __syncthreads();
    half8 af[4], bf[4];
#pragma unroll
    for (int mr = 0; mr < 4; ++mr) {
      int row = wr * 64 + mr * 16 + lr;
      int cq = ko ^ ((row >> 2) & 3);
      af[mr] = *(const half8*)(As + row * 32 + cq * 8);
    }
#pragma unroll
    for (int nc = 0; nc < 4; ++nc) {
      int col = wc * 64 + nc * 16 + lr;
      int cq = ko ^ ((col >> 2) & 3);
      bf[nc] = *(const half8*)(Bs + col * 32 + cq * 8);
    }
#pragma unroll
    for (int mr = 0; mr < 4; ++mr)
#pragma unroll
      for (int nc = 0; nc < 4; ++nc)
        acc[mr][nc] = __builtin_amdgcn_mfma_f32_16x16x32_f16(af[mr], bf[nc], acc[mr][nc], 0, 0, 0);
  }

  const int lq = l >> 4;
#pragma unroll
  for (int nc = 0; nc < 4; ++nc) {
    int gcol = blockIdx.y * 128 + wc * 64 + nc * 16 + lr;
    float bia = bias0[gcol];
    if (EPI == 1) bia += bias1[gcol];
#pragma unroll
    for (int mr = 0; mr < 4; ++mr) {
      int grow = blockIdx.x * 128 + wr * 64 + mr * 16 + lq * 4;
#pragma unroll
      for (int i = 0; i < 4; ++i) {
        float v = acc[mr][nc][i] + bia;
        if (EPI == 0) v = v * sigmoidf_(v);
        C[(size_t)(grow + i) * N + gcol] = (_Float16)v;
      }
    }
  }
}

// ---------------- persistent LSTM scan (tagged speculation) -----------------
// 64 blocks x 256 threads.  hT[2][32][512] tagged 8B slots.  Per step:
//   speculative 64-slot payload read (NO poll) -> tag validate
//   miss: per-wave flag poll (R10 mapping) -> one re-read
//   MFMA -> red[t&1] staging -> lgkmcnt(0)+s_barrier (only barrier)
//   gates -> tagged h-store -> per-wave vmcnt drain -> lane0 wave-flag
//   background: outh store, out_hn/cn, gx prefetch t+1
__global__ __launch_bounds__(256, 1) void k_scan(
    const _Float16* __restrict__ gx,    // [32][512][4096]
    const _Float16* __restrict__ Whh,   // [4096][1024] f16
    const float* __restrict__ cxs,      // [32][1024]
    ull* __restrict__ hT,               // [2][32][512] tagged pairs
    int* __restrict__ flags,            // [64][4] x16-int padded
    _Float16* __restrict__ outh,        // [32][512][1024]
    float* __restrict__ out_hn, float* __restrict__ out_cn)
{
  const int blk = blockIdx.x;           // 0..63
  const int hbase = blk * 16;
  const int tid = threadIdx.x, l = tid & 63, wq = tid >> 6;
  __shared__ float red[2][4][4][2][4][64]; // [parity][wave][gate][mtile][reg][lane]

  const int cc = l & 15, ko = l >> 4;

  // B-frag preload: lane holds gate col q*1024+hbase+cc, k = wq*256+kk*32+ko*8
  half8 bfr[4][8];
#pragma unroll
  for (int q = 0; q < 4; ++q)
#pragma unroll
    for (int kk = 0; kk < 8; ++kk)
      bfr[q][kk] = *(const half8*)(Whh + (size_t)(q * 1024 + hbase + cc) * 1024
                                   + wq * 256 + kk * 32 + ko * 8);

  // gate-phase ownership: thread -> (batch gb, col pair gc2)
  const int gb = tid >> 3, gc2 = tid & 7;
  float c0 = cxs[gb * 1024 + hbase + gc2 * 2 + 0];
  float c1 = cxs[gb * 1024 + hbase + gc2 * 2 + 1];
  const int gmt = gb >> 4, greg = gb & 3;
  const int lane0 = ((gb & 15) >> 2) * 16 + gc2 * 2;

  // per-wave poll target: lane l watches (block 16wq+(l&15), wave l>>4)
  const int* myflag = flags + ((wq * 16 + (l & 15)) * 4 + (l >> 4)) * 16;
  int* ourflag = flags + (blk * 4 + wq) * 16;

  // prologue: gx prefetch for t=0
  unsigned gxv[4];
#pragma unroll
  for (int q = 0; q < 4; ++q)
    gxv[q] = *(const unsigned*)(gx + (size_t)gb * 512 * 4096
                                + q * 1024 + hbase + gc2 * 2);

  for (int t = 0; t < 512; ++t) {
    // ---- speculative tagged payload read (no poll) ----------------------
    const ull* base0 = hT + (size_t)(t & 1) * 16384 + (size_t)cc * 512;
    const ull* base1 = base0 + 16 * 512;
    const unsigned tgt = (unsigned)(t + 1);
    ull ld0[32], ld1[32];
#pragma unroll
    for (int kk = 0; kk < 8; ++kk)
#pragma unroll
      for (int j = 0; j < 4; ++j) {
        int p = wq * 128 + kk * 16 + ko * 4 + j;
        ld0[kk * 4 + j] = __hip_atomic_load(base0 + p, __ATOMIC_RELAXED, __HIP_MEMORY_SCOPE_AGENT);
        ld1[kk * 4 + j] = __hip_atomic_load(base1 + p, __ATOMIC_RELAXED, __HIP_MEMORY_SCOPE_AGENT);
      }
    bool ok = true;
#pragma unroll
    for (int i = 0; i < 32; ++i)
      ok &= ((unsigned)(ld0[i] >> 32) >= tgt) & ((unsigned)(ld1[i] >> 32) >= tgt);
    if (!__all(ok)) {
      // ---- sound fallback: per-wave flag poll, then ONE re-read ----------
      int guard = 0;
      while (true) {
        int f = __hip_atomic_load(myflag, __ATOMIC_RELAXED, __HIP_MEMORY_SCOPE_AGENT);
        if (__all(f >= t)) break;
        if (++guard > (1 << 17)) break;   // fail loud, not hang
        __builtin_amdgcn_s_sleep(1);
      }
      asm volatile("" ::: "memory");
      __builtin_amdgcn_sched_barrier(0);
#pragma unroll
      for (int kk = 0; kk < 8; ++kk)
#pragma unroll
        for (int j = 0; j < 4; ++j) {
          int p = wq * 128 + kk * 16 + ko * 4 + j;
          ld0[kk * 4 + j] = __hip_atomic_load(base0 + p, __ATOMIC_RELAXED, __HIP_MEMORY_SCOPE_AGENT);
          ld1[kk * 4 + j] = __hip_atomic_load(base1 + p, __ATOMIC_RELAXED, __HIP_MEMORY_SCOPE_AGENT);
        }
    }

    floatx4 acc[4][2];
#pragma unroll
    for (int q = 0; q < 4; ++q) {
      acc[q][0] = (floatx4){0.f, 0.f, 0.f, 0.f};
      acc[q][1] = (floatx4){0.f, 0.f, 0.f, 0.f};
    }
#pragma unroll
    for (int kk = 0; kk < 8; ++kk) {
      union { unsigned u[4]; half8 h; } a0, a1;
#pragma unroll
      for (int j = 0; j < 4; ++j) {
        a0.u[j] = (unsigned)ld0[kk * 4 + j];
        a1.u[j] = (unsigned)ld1[kk * 4 + j];
      }
#pragma unroll
      for (int q = 0; q < 4; ++q) {
        acc[q][0] = __builtin_amdgcn_mfma_f32_16x16x32_f16(a0.h, bfr[q][kk], acc[q][0], 0, 0, 0);
        acc[q][1] = __builtin_amdgcn_mfma_f32_16x16x32_f16(a1.h, bfr[q][kk], acc[q][1], 0, 0, 0);
      }
    }
    // parity-indexed reduce staging
    const int pp = t & 1;
#pragma unroll
    for (int q = 0; q < 4; ++q)
#pragma unroll
      for (int mt = 0; mt < 2; ++mt)
#pragma unroll
        for (int i = 0; i < 4; ++i)
          red[pp][wq][q][mt][i][l] = acc[q][mt][i];
    asm volatile("s_waitcnt lgkmcnt(0)" ::: "memory");   // LDS writes done
    __builtin_amdgcn_s_barrier();   // ONLY barrier: join waves + WAR certify
    __builtin_amdgcn_sched_barrier(0);

    // gate phase: all 256 threads, (batch gb, cols 2gc2, 2gc2+1)
    float pre0[4], pre1[4];
#pragma unroll
    for (int q = 0; q < 4; ++q) {
      pre0[q] = red[pp][0][q][gmt][greg][lane0] + red[pp][1][q][gmt][greg][lane0]
              + red[pp][2][q][gmt][greg][lane0] + red[pp][3][q][gmt][greg][lane0];
      pre1[q] = red[pp][0][q][gmt][greg][lane0 + 1] + red[pp][1][q][gmt][greg][lane0 + 1]
              + red[pp][2][q][gmt][greg][lane0 + 1] + red[pp][3][q][gmt][greg][lane0 + 1];
    }
    union { unsigned u; _Float16 h[2]; } g0, g1, g2, g3;
    g0.u = gxv[0]; g1.u = gxv[1]; g2.u = gxv[2]; g3.u = gxv[3];

    float i0 = sigmoidf_(pre0[0] + (float)g0.h[0]);
    float f0 = sigmoidf_(pre0[1] + (float)g1.h[0]);
    float gg0 = tanhf_(pre0[2] + (float)g2.h[0]);
    float o0 = sigmoidf_(pre0[3] + (float)g3.h[0]);
    c0 = f0 * c0 + i0 * gg0;
    float h0 = o0 * tanhf_(c0);

    float i1 = sigmoidf_(pre1[0] + (float)g0.h[1]);
    float f1 = sigmoidf_(pre1[1] + (float)g1.h[1]);
    float gg1 = tanhf_(pre1[2] + (float)g2.h[1]);
    float o1 = sigmoidf_(pre1[3] + (float)g3.h[1]);
    c1 = f1 * c1 + i1 * gg1;
    float h1 = o1 * tanhf_(c1);

    union { _Float16 h[2]; unsigned u; } hp;
    hp.h[0] = (_Float16)h0; hp.h[1] = (_Float16)h1;

    // CRITICAL TAIL (per-wave): tagged h-store -> drain -> wave-flag
    ull st = (ull)hp.u | ((ull)(unsigned)(t + 2) << 32);
    __hip_atomic_store(hT + (size_t)((t + 1) & 1) * 16384 + gb * 512 + blk * 8 + gc2,
                       st, __ATOMIC_RELAXED, __HIP_MEMORY_SCOPE_AGENT);
    asm volatile("s_waitcnt vmcnt(0)" ::: "memory");  // per-wave drain
    __builtin_amdgcn_sched_barrier(0);
    if (l == 0 && t < 511)
      __hip_atomic_store(ourflag, t + 1, __ATOMIC_RELAXED,
                         __HIP_MEMORY_SCOPE_AGENT);

    // BACKGROUND (latency absorbed by next step's speculative window):
    *(unsigned*)(outh + ((size_t)gb * 512 + t) * 1024 + hbase + gc2 * 2) = hp.u;
    if (t == 511) {
      float2 hv; hv.x = h0; hv.y = h1;
      float2 cv; cv.x = c0; cv.y = c1;
      *(float2*)(out_hn + gb * 1024 + hbase + gc2 * 2) = hv;
      *(float2*)(out_cn + gb * 1024 + hbase + gc2 * 2) = cv;
    } else {
#pragma unroll
      for (int q = 0; q < 4; ++q)
        gxv[q] = *(const unsigned*)(gx + ((size_t)gb * 512 + t + 1) * 4096
                                    + q * 1024 + hbase + gc2 * 2);
    }
    __builtin_amdgcn_sched_barrier(0);  // pin background issue before backedge
  }
}

// ---------------- LayerNorm (per row of 1024) + ar partial ------------------
__global__ __launch_bounds__(256) void k_ln(
    const _Float16* __restrict__ x, const float* __restrict__ gam,
    const float* __restrict__ bet, _Float16* __restrict__ y,
    float* __restrict__ arpart)
{
  const int m = blockIdx.x;
  const int tid = threadIdx.x;
  const int w = tid >> 6, l = tid & 63;
  half4v v = *(const half4v*)(x + (size_t)m * 1024 + tid * 4);
  float xv[4]; float s = 0.f, ss = 0.f;
#pragma unroll
  for (int j = 0; j < 4; ++j) { xv[j] = (float)v[j]; s += xv[j]; ss += xv[j] * xv[j]; }
#pragma unroll
  for (int off = 32; off > 0; off >>= 1) { s += __shfl_xor(s, off, 64); ss += __shfl_xor(ss, off, 64); }
  __shared__ float sw[4], ssw[4], bcast[2];
  if (l == 0) { sw[w] = s; ssw[w] = ss; }
  __syncthreads();
  if (tid == 0) {
    float S = sw[0] + sw[1] + sw[2] + sw[3];
    float SS = ssw[0] + ssw[1] + ssw[2] + ssw[3];
    float mu = S * (1.f / 1024.f);
    float var = SS * (1.f / 1024.f) - mu * mu;
    bcast[0] = mu; bcast[1] = rsqrtf(var + 1e-5f);
  }
  __syncthreads();
  float mu = bcast[0], rstd = bcast[1];
  float part = 0.f; half4v o;
#pragma unroll
  for (int j = 0; j < 4; ++j) {
    float nv = (xv[j] - mu) * rstd * gam[tid * 4 + j] + bet[tid * 4 + j];
    o[j] = (_Float16)nv;
    part += nv * nv;
  }
  *(half4v*)(y + (size_t)m * 1024 + tid * 4) = o;
#pragma unroll
  for (int off = 32; off > 0; off >>= 1) part += __shfl_xor(part, off, 64);
  if (l == 0) sw[w] = part;
  __syncthreads();
  if (tid == 0) arpart[m] = sw[0] + sw[1] + sw[2] + sw[3];
}

// ---------------- temporal-diff loss partials -------------------------------
__global__ __launch_bounds__(256) void k_tar(const _Float16* __restrict__ y, float* __restrict__ tarpart) {
  const int tid = threadIdx.x;
  int gid = blockIdx.x * 256 + tid;
  const int stride = gridDim.x * 256;
  const int TOT = 32 * 511 * 256;  // vec4 groups
  float s = 0.f;
  for (int v = gid; v < TOT; v += stride) {
    int b = v / (511 * 256);
    int r = v - b * (511 * 256);
    size_t base = (size_t)b * 512 * 1024 + (size_t)r * 4;
    half4v a = *(const half4v*)(y + base);
    half4v c = *(const half4v*)(y + base + 1024);
#pragma unroll
    for (int j = 0; j < 4; ++j) { float d = (float)c[j] - (float)a[j]; s += d * d; }
  }
#pragma unroll
  for (int off = 32; off > 0; off >>= 1) s += __shfl_xor(s, off, 64);
  __shared__ float sw[4];
  if ((tid & 63) == 0) sw[tid >> 6] = s;
  __syncthreads();
  if (tid == 0) tarpart[blockIdx.x] = sw[0] + sw[1] + sw[2] + sw[3];
}

__global__ __launch_bounds__(256) void k_reduce(
    const float* __restrict__ arpart, const float* __restrict__ tarpart,
    float* __restrict__ dst)
{
  const int tid = threadIdx.x;
  float a = 0.f, t = 0.f;
  for (int i = tid; i < 16384; i += 256) a += arpart[i];
  for (int i = tid; i < 2048; i += 256) t += tarpart[i];
#pragma unroll
  for (int off = 32; off > 0; off >>= 1) { a += __shfl_xor(a, off, 64); t += __shfl_xor(t, off, 64); }
  __shared__ float sa[4], st[4];
  if ((tid & 63) == 0) { sa[tid >> 6] = a; st[tid >> 6] = t; }
  __syncthreads();
  if (tid == 0) {
    dst[0] = (sa[0] + sa[1] + sa[2] + sa[3]) * (0.01f / 16777216.f);
    dst[1] = (st[0] + st[1] + st[2] + st[3]) * (0.01f / 16744448.f);
  }
}

// ---------------- logits head: [16384,1024] @ [64,1024]^T + ba --------------
__global__ __launch_bounds__(256) void k_logits(
    const _Float16* __restrict__ X, const _Float16* __restrict__ Wa,
    const float* __restrict__ ba, float* __restrict__ out)
{
  const int tid = threadIdx.x, l = tid & 63, w = tid >> 6;
  const int lr = l & 15, lq = l >> 4;
  const int rowb = blockIdx.x * 64 + w * 16;
  floatx4 acc[4];
#pragma unroll
  for (int nc = 0; nc < 4; ++nc) acc[nc] = (floatx4){0.f, 0.f, 0.f, 0.f};
  for (int kc = 0; kc < 32; ++kc) {
    int k = kc * 32 + lq * 8;
    half8 af = *(const half8*)(X + (size_t)(rowb + lr) * 1024 + k);
#pragma unroll
    for (int nc = 0; nc < 4; ++nc) {
      half8 bf = *(const half8*)(Wa + (size_t)(nc * 16 + lr) * 1024 + k);
      acc[nc] = __builtin_amdgcn_mfma_f32_16x16x32_f16(af, bf, acc[nc], 0, 0, 0);
    }
  }
#pragma unroll
  for (int nc = 0; nc < 4; ++nc) {
    int col = nc * 16 + lr;
    float bia = ba[col];
#pragma unroll
    for (int i = 0; i < 4; ++i) {
      int grow = rowb + lq * 4 + i;
      out[(size_t)grow * 64 + col] = acc[nc][i] + bia;
    }
  }
}

// ---------------- value head: dot(row, Wc) + bc -----------------------------
__global__ __launch_bounds__(256) void k_values(
    const _Float16* __restrict__ X, const _Float16* __restrict__ Wc,
    const float* __restrict__ bc, float* __restrict__ out)
{
  const int tid = threadIdx.x, l = tid & 63, w = tid >> 6;
  half8 w0 = *(const half8*)(Wc + l * 16);
  half8 w1 = *(const half8*)(Wc + l * 16 + 8);
  float bias = bc[0];
  const int rowb = blockIdx.x * 64 + w * 16;
  for (int r = 0; r < 16; ++r) {
    const _Float16* xr = X + (size_t)(rowb + r) * 1024 + l * 16;
    half8 x0 = *(const half8*)(xr);
    half8 x1 = *(const half8*)(xr + 8);
    float s = 0.f;
#pragma unroll
    for (int j = 0; j < 8; ++j) s += (float)x0[j] * (float)w0[j] + (float)x1[j] * (float)w1[j];
#pragma unroll
    for (int off = 32; off > 0; off >>= 1) s += __shfl_xor(s, off, 64);
    if (l == 0) out[rowb + r] = s + bias;
  }
}

// ---------------------------------------------------------------------------
extern "C" void kernel_launch(void* const* d_in, const int* in_sizes, int n_in,
                              void* d_out, int out_size, void* d_ws, size_t ws_size,
                              hipStream_t stream)
{
  const float* obs = (const float*)d_in[0];
  const float* hxs = (const float*)d_in[1];
  const float* cxs = (const float*)d_in[2];
  const float* W1  = (const float*)d_in[3];
  const float* b1  = (const float*)d_in[4];
  const float* W2  = (const float*)d_in[5];
  const float* b2  = (const float*)d_in[6];
  const float* Wih = (const float*)d_in[7];
  const float* Whh = (const float*)d_in[8];
  const float* bih = (const float*)d_in[9];
  const float* bhh = (const float*)d_in[10];
  const float* lng = (const float*)d_in[11];
  const float* lnb = (const float*)d_in[12];
  const float* Wa  = (const float*)d_in[13];
  const float* ba  = (const float*)d_in[14];
  const float* Wc  = (const float*)d_in[15];
  const float* bc  = (const float*)d_in[16];

  char* ws = (char*)d_ws;
  size_t off = 0;
  auto alloc = [&](size_t bytes) -> char* {
    char* p = ws + off;
    off += (bytes + 255) & ~(size_t)255;
    return p;
  };
  _Float16* obs16 = (_Float16*)alloc(4194304ull * 2);
  _Float16* W1x   = (_Float16*)alloc(262144ull * 2);
  _Float16* W2x   = (_Float16*)alloc(1048576ull * 2);
  _Float16* Wihx  = (_Float16*)alloc(4194304ull * 2);
  _Float16* Whhx  = (_Float16*)alloc(4194304ull * 2);
  _Float16* Wax   = (_Float16*)alloc(65536ull * 2);
  _Float16* Wcx   = (_Float16*)alloc(1024ull * 2);
  _Float16* enc1  = (_Float16*)alloc(16384ull * 1024 * 2);
  _Float16* enc2  = (_Float16*)alloc(16384ull * 1024 * 2);
  _Float16* gx    = (_Float16*)alloc(16384ull * 4096 * 2);
  ull* hT         = (ull*)alloc(2ull * 16384 * 8);     // tagged h, 256KB
  int* flags      = (int*)alloc(64ull * 4 * 16 * 4);   // [64][4] 64B-padded
  _Float16* outh  = (_Float16*)alloc(16384ull * 1024 * 2);
  float* arpart   = (float*)alloc(16384ull * 4);
  float* tarpart  = (float*)alloc(2048ull * 4);
  _Float16* normed = enc1;   // enc1 dead after G2 -> reuse for LN output

  float* out_f      = (float*)d_out;
  float* out_logits = out_f;                 // 1048576
  float* out_values = out_f + 1048576;       // 16384
  float* out_hn     = out_f + 1064960;       // 32768
  float* out_cn     = out_f + 1097728;       // 32768
  float* out_loss   = out_f + 1130496;       // 2

  // reset tags+flags every call (replay safety), then write tagged h_0
  hipMemsetAsync(hT, 0, 2ull * 16384 * 8, stream);
  hipMemsetAsync(flags, 0, 64ull * 4 * 16 * 4, stream);
  k_inith<<<64, 256, 0, stream>>>(hxs, hT);

  // all f32->f16 conversions in one launch
  k_convert_all<<<2048, 256, 0, stream>>>(
      obs, obs16, 4194304 / 4,
      W1, W1x, 262144 / 4,
      W2, W2x, 1048576 / 4,
      Wih, Wihx, 4194304 / 4,
      Whh, Whhx, 4194304 / 4,
      Wa, Wax, 65536 / 4,
      Wc, Wcx, 1024 / 4);

  // encoder
  k_gemm<0><<<dim3(128, 8), 256, 0, stream>>>(obs16, W1x, enc1, b1, nullptr, 16384, 1024, 256);
  k_gemm<0><<<dim3(128, 8), 256, 0, stream>>>(enc1, W2x, enc2, b2, nullptr, 16384, 1024, 1024);
  // gx = enc2 @ W_ih^T + b_ih + b_hh
  k_gemm<1><<<dim3(128, 32), 256, 0, stream>>>(enc2, Wihx, gx, bih, bhh, 16384, 4096, 1024);
  // LSTM scan (64 persistent blocks, tagged speculation + flag fallback)
  k_scan<<<64, 256, 0, stream>>>(gx, Whhx, cxs, hT, flags, outh, out_hn, out_cn);
  // LayerNorm + losses
  k_ln<<<16384, 256, 0, stream>>>(outh, lng, lnb, normed, arpart);
  k_tar<<<2048, 256, 0, stream>>>(normed, tarpart);
  k_reduce<<<1, 256, 0, stream>>>(arpart, tarpart, out_loss);
  // heads
  k_logits<<<256, 256, 0, stream>>>(normed, Wax, ba, out_logits);
  k_values<<<256, 256, 0, stream>>>(normed, Wcx, bc, out_values);
  (void)in_sizes; (void)n_in; (void)out_size; (void)ws_size;
}

// Round 13
// 3343.279 us; speedup vs baseline: 2.1456x; 2.1456x over previous
//
#include <hip/hip_runtime.h>

// ---------------------------------------------------------------------------
// LSTMPPOPolicy: encoder(2x Linear+SiLU) -> LSTM(T=512 scan) -> LN -> heads
// B=32 T=512 OBS=256 ENC=1024 H=1024 A=64.  fp16 MFMA (f32 accum).
// R13 = R9 restored (best measured: 3,342us total; scan 3,006us = 5.87us/step).
// Search summary: 7 scan-protocol variants (contended-atomic, flag-array,
// fence-free sc1, tagged-data x3, 2-phase, raw-barrier, minimal-drain,
// per-wave-decoupled, gx-fusion) bracket the floor at ~5.9us/step:
//   - detect CANNOT merge into data load (R4/R6/R12: consumer arrives before
//     producer stores are MALL-visible; retry re-reads congest the fabric)
//   - per-step cost = poll-detect + payload RT + compute + minimal drain;
//     all removable overheads (agent fences, full drains, barrier count,
//     convoy fan-in) have been removed or shown null.
// The scan is latency-bound (2% HBM, 2% MFMA): 512 serialized MALL-scope
// exchanges x ~5.9us.  Not a roofline problem; structural floor for HIP.
// ---------------------------------------------------------------------------

typedef _Float16 half8 __attribute__((ext_vector_type(8)));
typedef _Float16 half4v __attribute__((ext_vector_type(4)));
typedef float floatx4 __attribute__((ext_vector_type(4)));
typedef unsigned long long ull;

__device__ __forceinline__ float sigmoidf_(float x) { return 1.f / (1.f + __expf(-x)); }
__device__ __forceinline__ float tanhf_(float x) {
  x = fminf(15.f, fmaxf(-15.f, x));
  float e = __expf(-2.f * x);
  return (1.f - e) / (1.f + e);
}

// ---------------- merged f32 -> f16 convert (8 segments, grid-stride) ------
__global__ __launch_bounds__(256) void k_convert_all(
    const float* s0, _Float16* d0, int n0,   // vec4 counts
    const float* s1, _Float16* d1, int n1,
    const float* s2, _Float16* d2, int n2,
    const float* s3, _Float16* d3, int n3,
    const float* s4, _Float16* d4, int n4,
    const float* s5, _Float16* d5, int n5,
    const float* s6, _Float16* d6, int n6,
    const float* s7, _Float16* d7, int n7)
{
  const int gid = blockIdx.x * 256 + threadIdx.x;
  const int stride = gridDim.x * 256;
#define CONV_SEG(s, d, n)                                                  \
  for (int i = gid; i < (n); i += stride) {                                \
    floatx4 v = *(const floatx4*)((s) + (size_t)i * 4);                    \
    half4v h;                                                              \
    h[0] = (_Float16)v[0]; h[1] = (_Float16)v[1];                          \
    h[2] = (_Float16)v[2]; h[3] = (_Float16)v[3];                          \
    *(half4v*)((d) + (size_t)i * 4) = h;                                   \
  }
  CONV_SEG(s0, d0, n0)
  CONV_SEG(s1, d1, n1)
  CONV_SEG(s2, d2, n2)
  CONV_SEG(s3, d3, n3)
  CONV_SEG(s4, d4, n4)
  CONV_SEG(s5, d5, n5)
  CONV_SEG(s6, d6, n6)
  CONV_SEG(s7, d7, n7)
#undef CONV_SEG
}

// ---------------- fp16 MFMA GEMM: C = epi(A @ B^T + bias) ------------------
template<int EPI>
__global__ __launch_bounds__(256) void k_gemm(
    const _Float16* __restrict__ A, const _Float16* __restrict__ B,
    _Float16* __restrict__ C, const float* __restrict__ bias0,
    const float* __restrict__ bias1, int M, int N, int K)
{
  __shared__ _Float16 As[128 * 32];
  __shared__ _Float16 Bs[128 * 32];
  const int tid = threadIdx.x;
  const int l = tid & 63;
  const int w = tid >> 6;
  const int wr = w >> 1, wc = w & 1;
  const _Float16* Ab = A + (size_t)blockIdx.x * 128 * K;
  const _Float16* Bb = B + (size_t)blockIdx.y * 128 * K;

  floatx4 acc[4][4];
#pragma unroll
  for (int a = 0; a < 4; ++a)
#pragma unroll
    for (int b = 0; b < 4; ++b) acc[a][b] = (floatx4){0.f, 0.f, 0.f, 0.f};

  const int ci0 = tid, ci1 = tid + 256;
  const int r0 = ci0 >> 2, r1 = ci1 >> 2;
  const int q0 = (ci0 & 3) ^ ((r0 >> 2) & 3);
  const int q1 = (ci1 & 3) ^ ((r1 >> 2) & 3);
  const int lr = l & 15;
  const int ko = l >> 4;
  const int nkt = K >> 5;

  for (int kt = 0; kt < nkt; ++kt) {
    const _Float16* Ak = Ab + kt * 32;
    const _Float16* Bk = Bb + kt * 32;
    uint4 va0 = *(const uint4*)(Ak + (size_t)r0 * K + q0 * 8);
    uint4 va1 = *(const uint4*)(Ak + (size_t)r1 * K + q1 * 8);
    uint4 vb0 = *(const uint4*)(Bk + (size_t)r0 * K + q0 * 8);
    uint4 vb1 = *(const uint4*)(Bk + (size_t)r1 * K + q1 * 8);
    __syncthreads();
    *(uint4*)(As + ci0 * 8) = va0;
    *(uint4*)(As + ci1 * 8) = va1;
    *(uint4*)(Bs + ci0 * 8) = vb0;
    *(uint4*)(Bs + ci1 * 8) = vb1;
    __syncthreads();
    half8 af[4], bf[4];
#pragma unroll
    for (int mr = 0; mr < 4; ++mr) {
      int row = wr * 64 + mr * 16 + lr;
      int cq = ko ^ ((row >> 2) & 3);
      af[mr] = *(const half8*)(As + row * 32 + cq * 8);
    }
#pragma unroll
    for (int nc = 0; nc < 4; ++nc) {
      int col = wc * 64 + nc * 16 + lr;
      int cq = ko ^ ((col >> 2) & 3);
      bf[nc] = *(const half8*)(Bs + col * 32 + cq * 8);
    }
#pragma unroll
    for (int mr = 0; mr < 4; ++mr)
#pragma unroll
      for (int nc = 0; nc < 4; ++nc)
        acc[mr][nc] = __builtin_amdgcn_mfma_f32_16x16x32_f16(af[mr], bf[nc], acc[mr][nc], 0, 0, 0);
  }

  const int lq = l >> 4;
#pragma unroll
  for (int nc = 0; nc < 4; ++nc) {
    int gcol = blockIdx.y * 128 + wc * 64 + nc * 16 + lr;
    float bia = bias0[gcol];
    if (EPI == 1) bia += bias1[gcol];
#pragma unroll
    for (int mr = 0; mr < 4; ++mr) {
      int grow = blockIdx.x * 128 + wr * 64 + mr * 16 + lq * 4;
#pragma unroll
      for (int i = 0; i < 4; ++i) {
        float v = acc[mr][nc][i] + bia;
        if (EPI == 0) v = v * sigmoidf_(v);
        C[(size_t)(grow + i) * N + gcol] = (_Float16)v;
      }
    }
  }
}

// ---------------- persistent LSTM scan (minimal drain, R9) ------------------
// 64 blocks x 256 threads.  Per step:
//   all waves poll flags>=t (64 lanes x 1 flag, s_sleep backoff)
//   32 x 8B sc1 h-loads -> MFMA (compiler counted waits)
//   red staging -> lgkmcnt(0) + raw s_barrier
//   gates -> h-store (4B sc1) -> vmcnt(0) -> raw s_barrier
//   tid0: flag=t+1   (critical path ends here)
//   background: outh store, out_hn/cn (t=511), gx prefetch t+1
__global__ __launch_bounds__(256, 1) void k_scan(
    const _Float16* __restrict__ gx,    // [32][512][4096]
    const _Float16* __restrict__ Whh,   // [4096][1024] f16
    const float* __restrict__ cxs,      // [32][1024]
    _Float16* __restrict__ hstate,      // [2][32][1024]
    int* __restrict__ flags,            // [64] x16-int padded
    _Float16* __restrict__ outh,        // [32][512][1024]
    float* __restrict__ out_hn, float* __restrict__ out_cn)
{
  const int blk = blockIdx.x;           // 0..63
  const int hbase = blk * 16;
  const int tid = threadIdx.x, l = tid & 63, wq = tid >> 6;
  __shared__ float red[4][4][2][4][65]; // [wave][gate][mtile][reg][lane+pad]

  const int cc = l & 15, ko = l >> 4;

  // B-frag preload: lane holds gate col q*1024+hbase+cc, k = wq*256+kk*32+ko*8
  half8 bfr[4][8];
#pragma unroll
  for (int q = 0; q < 4; ++q)
#pragma unroll
    for (int kk = 0; kk < 8; ++kk)
      bfr[q][kk] = *(const half8*)(Whh + (size_t)(q * 1024 + hbase + cc) * 1024
                                   + wq * 256 + kk * 32 + ko * 8);

  // gate-phase ownership: thread -> (batch gb, col pair gc2)
  const int gb = tid >> 3, gc2 = tid & 7;
  float c0 = cxs[gb * 1024 + hbase + gc2 * 2 + 0];
  float c1 = cxs[gb * 1024 + hbase + gc2 * 2 + 1];
  const int gmt = gb >> 4, greg = gb & 3;
  const int lane0 = ((gb & 15) >> 2) * 16 + gc2 * 2;

  // prologue: gx prefetch for t=0
  unsigned gxv[4];
#pragma unroll
  for (int q = 0; q < 4; ++q)
    gxv[q] = *(const unsigned*)(gx + (size_t)gb * 512 * 4096
                                + q * 1024 + hbase + gc2 * 2);

  for (int t = 0; t < 512; ++t) {
    if (t > 0) {
      // all-wave poll: lane l watches producer-block l's flag (4B sc1)
      const int* fp = flags + l * 16;
      int guard = 0;
      while (true) {
        int f = __hip_atomic_load(fp, __ATOMIC_RELAXED, __HIP_MEMORY_SCOPE_AGENT);
        if (__all(f >= t)) break;
        if (++guard > (1 << 17)) break;   // fail loud, not hang
        __builtin_amdgcn_s_sleep(1);
      }
      asm volatile("" ::: "memory");
      __builtin_amdgcn_sched_barrier(0);
    }

    // h-loads: 32 x 8B sc1 per lane; compiler inserts counted waits at use
    const _Float16* hcur = hstate + (size_t)(t & 1) * 32768;
    const ull* p0 = (const ull*)(hcur + cc * 1024 + wq * 256 + ko * 8);
    const ull* p1 = (const ull*)(hcur + (16 + cc) * 1024 + wq * 256 + ko * 8);
    ull ld0[16], ld1[16];
#pragma unroll
    for (int kk = 0; kk < 8; ++kk) {
      ld0[kk * 2 + 0] = __hip_atomic_load(p0 + kk * 8 + 0, __ATOMIC_RELAXED, __HIP_MEMORY_SCOPE_AGENT);
      ld0[kk * 2 + 1] = __hip_atomic_load(p0 + kk * 8 + 1, __ATOMIC_RELAXED, __HIP_MEMORY_SCOPE_AGENT);
      ld1[kk * 2 + 0] = __hip_atomic_load(p1 + kk * 8 + 0, __ATOMIC_RELAXED, __HIP_MEMORY_SCOPE_AGENT);
      ld1[kk * 2 + 1] = __hip_atomic_load(p1 + kk * 8 + 1, __ATOMIC_RELAXED, __HIP_MEMORY_SCOPE_AGENT);
    }

    floatx4 acc[4][2];
#pragma unroll
    for (int q = 0; q < 4; ++q) {
      acc[q][0] = (floatx4){0.f, 0.f, 0.f, 0.f};
      acc[q][1] = (floatx4){0.f, 0.f, 0.f, 0.f};
    }
#pragma unroll
    for (int kk = 0; kk < 8; ++kk) {
      union { ull u2[2]; half8 h; } a0, a1;
      a0.u2[0] = ld0[kk * 2 + 0]; a0.u2[1] = ld0[kk * 2 + 1];
      a1.u2[0] = ld1[kk * 2 + 0]; a1.u2[1] = ld1[kk * 2 + 1];
#pragma unroll
      for (int q = 0; q < 4; ++q) {
        acc[q][0] = __builtin_amdgcn_mfma_f32_16x16x32_f16(a0.h, bfr[q][kk], acc[q][0], 0, 0, 0);
        acc[q][1] = __builtin_amdgcn_mfma_f32_16x16x32_f16(a1.h, bfr[q][kk], acc[q][1], 0, 0, 0);
      }
    }
    // transposed reduce staging
#pragma unroll
    for (int q = 0; q < 4; ++q)
#pragma unroll
      for (int mt = 0; mt < 2; ++mt)
#pragma unroll
        for (int i = 0; i < 4; ++i)
          red[wq][q][mt][i][l] = acc[q][mt][i];
    asm volatile("s_waitcnt lgkmcnt(0)" ::: "memory");   // LDS writes done
    __builtin_amdgcn_s_barrier();                         // raw barrier
    __builtin_amdgcn_sched_barrier(0);

    // gate phase: all 256 threads, (batch gb, cols 2gc2, 2gc2+1)
    float pre0[4], pre1[4];
#pragma unroll
    for (int q = 0; q < 4; ++q) {
      pre0[q] = red[0][q][gmt][greg][lane0] + red[1][q][gmt][greg][lane0]
              + red[2][q][gmt][greg][lane0] + red[3][q][gmt][greg][lane0];
      pre1[q] = red[0][q][gmt][greg][lane0 + 1] + red[1][q][gmt][greg][lane0 + 1]
              + red[2][q][gmt][greg][lane0 + 1] + red[3][q][gmt][greg][lane0 + 1];
    }
    union { unsigned u; _Float16 h[2]; } g0, g1, g2, g3;
    g0.u = gxv[0]; g1.u = gxv[1]; g2.u = gxv[2]; g3.u = gxv[3];

    float i0 = sigmoidf_(pre0[0] + (float)g0.h[0]);
    float f0 = sigmoidf_(pre0[1] + (float)g1.h[0]);
    float gg0 = tanhf_(pre0[2] + (float)g2.h[0]);
    float o0 = sigmoidf_(pre0[3] + (float)g3.h[0]);
    c0 = f0 * c0 + i0 * gg0;
    float h0 = o0 * tanhf_(c0);

    float i1 = sigmoidf_(pre1[0] + (float)g0.h[1]);
    float f1 = sigmoidf_(pre1[1] + (float)g1.h[1]);
    float gg1 = tanhf_(pre1[2] + (float)g2.h[1]);
    float o1 = sigmoidf_(pre1[3] + (float)g3.h[1]);
    c1 = f1 * c1 + i1 * gg1;
    float h1 = o1 * tanhf_(c1);

    union { _Float16 h[2]; unsigned u; } hp;
    hp.h[0] = (_Float16)h0; hp.h[1] = (_Float16)h1;

    // CRITICAL PATH TAIL: h-store (4B sc1) -> drain it -> barrier -> flag
    __hip_atomic_store((unsigned*)(hstate + (size_t)((t + 1) & 1) * 32768
                                   + (size_t)gb * 1024 + hbase + gc2 * 2),
                       hp.u, __ATOMIC_RELAXED, __HIP_MEMORY_SCOPE_AGENT);
    asm volatile("s_waitcnt vmcnt(0)" ::: "memory");  // h-store ack only
    __builtin_amdgcn_sched_barrier(0);
    __builtin_amdgcn_s_barrier();                     // all 4 waves drained
    if (tid == 0 && t < 511)
      __hip_atomic_store(flags + blk * 16, t + 1, __ATOMIC_RELAXED,
                         __HIP_MEMORY_SCOPE_AGENT);

    // BACKGROUND (latency absorbed by next step's poll window):
    *(unsigned*)(outh + ((size_t)gb * 512 + t) * 1024 + hbase + gc2 * 2) = hp.u;
    if (t == 511) {
      float2 hv; hv.x = h0; hv.y = h1;
      float2 cv; cv.x = c0; cv.y = c1;
      *(float2*)(out_hn + gb * 1024 + hbase + gc2 * 2) = hv;
      *(float2*)(out_cn + gb * 1024 + hbase + gc2 * 2) = cv;
    } else {
#pragma unroll
      for (int q = 0; q < 4; ++q)
        gxv[q] = *(const unsigned*)(gx + ((size_t)gb * 512 + t + 1) * 4096
                                    + q * 1024 + hbase + gc2 * 2);
    }
    __builtin_amdgcn_sched_barrier(0);  // pin background issue before backedge
  }
}

// ---------------- LayerNorm (per row of 1024) + ar partial ------------------
__global__ __launch_bounds__(256) void k_ln(
    const _Float16* __restrict__ x, const float* __restrict__ gam,
    const float* __restrict__ bet, _Float16* __restrict__ y,
    float* __restrict__ arpart)
{
  const int m = blockIdx.x;
  const int tid = threadIdx.x;
  const int w = tid >> 6, l = tid & 63;
  half4v v = *(const half4v*)(x + (size_t)m * 1024 + tid * 4);
  float xv[4]; float s = 0.f, ss = 0.f;
#pragma unroll
  for (int j = 0; j < 4; ++j) { xv[j] = (float)v[j]; s += xv[j]; ss += xv[j] * xv[j]; }
#pragma unroll
  for (int off = 32; off > 0; off >>= 1) { s += __shfl_xor(s, off, 64); ss += __shfl_xor(ss, off, 64); }
  __shared__ float sw[4], ssw[4], bcast[2];
  if (l == 0) { sw[w] = s; ssw[w] = ss; }
  __syncthreads();
  if (tid == 0) {
    float S = sw[0] + sw[1] + sw[2] + sw[3];
    float SS = ssw[0] + ssw[1] + ssw[2] + ssw[3];
    float mu = S * (1.f / 1024.f);
    float var = SS * (1.f / 1024.f) - mu * mu;
    bcast[0] = mu; bcast[1] = rsqrtf(var + 1e-5f);
  }
  __syncthreads();
  float mu = bcast[0], rstd = bcast[1];
  float part = 0.f; half4v o;
#pragma unroll
  for (int j = 0; j < 4; ++j) {
    float nv = (xv[j] - mu) * rstd * gam[tid * 4 + j] + bet[tid * 4 + j];
    o[j] = (_Float16)nv;
    part += nv * nv;
  }
  *(half4v*)(y + (size_t)m * 1024 + tid * 4) = o;
#pragma unroll
  for (int off = 32; off > 0; off >>= 1) part += __shfl_xor(part, off, 64);
  if (l == 0) sw[w] = part;
  __syncthreads();
  if (tid == 0) arpart[m] = sw[0] + sw[1] + sw[2] + sw[3];
}

// ---------------- temporal-diff loss partials -------------------------------
__global__ __launch_bounds__(256) void k_tar(const _Float16* __restrict__ y, float* __restrict__ tarpart) {
  const int tid = threadIdx.x;
  int gid = blockIdx.x * 256 + tid;
  const int stride = gridDim.x * 256;
  const int TOT = 32 * 511 * 256;  // vec4 groups
  float s = 0.f;
  for (int v = gid; v < TOT; v += stride) {
    int b = v / (511 * 256);
    int r = v - b * (511 * 256);
    size_t base = (size_t)b * 512 * 1024 + (size_t)r * 4;
    half4v a = *(const half4v*)(y + base);
    half4v c = *(const half4v*)(y + base + 1024);
#pragma unroll
    for (int j = 0; j < 4; ++j) { float d = (float)c[j] - (float)a[j]; s += d * d; }
  }
#pragma unroll
  for (int off = 32; off > 0; off >>= 1) s += __shfl_xor(s, off, 64);
  __shared__ float sw[4];
  if ((tid & 63) == 0) sw[tid >> 6] = s;
  __syncthreads();
  if (tid == 0) tarpart[blockIdx.x] = sw[0] + sw[1] + sw[2] + sw[3];
}

__global__ __launch_bounds__(256) void k_reduce(
    const float* __restrict__ arpart, const float* __restrict__ tarpart,
    float* __restrict__ dst)
{
  const int tid = threadIdx.x;
  float a = 0.f, t = 0.f;
  for (int i = tid; i < 16384; i += 256) a += arpart[i];
  for (int i = tid; i < 2048; i += 256) t += tarpart[i];
#pragma unroll
  for (int off = 32; off > 0; off >>= 1) { a += __shfl_xor(a, off, 64); t += __shfl_xor(t, off, 64); }
  __shared__ float sa[4], st[4];
  if ((tid & 63) == 0) { sa[tid >> 6] = a; st[tid >> 6] = t; }
  __syncthreads();
  if (tid == 0) {
    dst[0] = (sa[0] + sa[1] + sa[2] + sa[3]) * (0.01f / 16777216.f);
    dst[1] = (st[0] + st[1] + st[2] + st[3]) * (0.01f / 16744448.f);
  }
}

// ---------------- logits head: [16384,1024] @ [64,1024]^T + ba --------------
__global__ __launch_bounds__(256) void k_logits(
    const _Float16* __restrict__ X, const _Float16* __restrict__ Wa,
    const float* __restrict__ ba, float* __restrict__ out)
{
  const int tid = threadIdx.x, l = tid & 63, w = tid >> 6;
  const int lr = l & 15, lq = l >> 4;
  const int rowb = blockIdx.x * 64 + w * 16;
  floatx4 acc[4];
#pragma unroll
  for (int nc = 0; nc < 4; ++nc) acc[nc] = (floatx4){0.f, 0.f, 0.f, 0.f};
  for (int kc = 0; kc < 32; ++kc) {
    int k = kc * 32 + lq * 8;
    half8 af = *(const half8*)(X + (size_t)(rowb + lr) * 1024 + k);
#pragma unroll
    for (int nc = 0; nc < 4; ++nc) {
      half8 bf = *(const half8*)(Wa + (size_t)(nc * 16 + lr) * 1024 + k);
      acc[nc] = __builtin_amdgcn_mfma_f32_16x16x32_f16(af, bf, acc[nc], 0, 0, 0);
    }
  }
#pragma unroll
  for (int nc = 0; nc < 4; ++nc) {
    int col = nc * 16 + lr;
    float bia = ba[col];
#pragma unroll
    for (int i = 0; i < 4; ++i) {
      int grow = rowb + lq * 4 + i;
      out[(size_t)grow * 64 + col] = acc[nc][i] + bia;
    }
  }
}

// ---------------- value head: dot(row, Wc) + bc -----------------------------
__global__ __launch_bounds__(256) void k_values(
    const _Float16* __restrict__ X, const _Float16* __restrict__ Wc,
    const float* __restrict__ bc, float* __restrict__ out)
{
  const int tid = threadIdx.x, l = tid & 63, w = tid >> 6;
  half8 w0 = *(const half8*)(Wc + l * 16);
  half8 w1 = *(const half8*)(Wc + l * 16 + 8);
  float bias = bc[0];
  const int rowb = blockIdx.x * 64 + w * 16;
  for (int r = 0; r < 16; ++r) {
    const _Float16* xr = X + (size_t)(rowb + r) * 1024 + l * 16;
    half8 x0 = *(const half8*)(xr);
    half8 x1 = *(const half8*)(xr + 8);
    float s = 0.f;
#pragma unroll
    for (int j = 0; j < 8; ++j) s += (float)x0[j] * (float)w0[j] + (float)x1[j] * (float)w1[j];
#pragma unroll
    for (int off = 32; off > 0; off >>= 1) s += __shfl_xor(s, off, 64);
    if (l == 0) out[rowb + r] = s + bias;
  }
}

// ---------------------------------------------------------------------------
extern "C" void kernel_launch(void* const* d_in, const int* in_sizes, int n_in,
                              void* d_out, int out_size, void* d_ws, size_t ws_size,
                              hipStream_t stream)
{
  const float* obs = (const float*)d_in[0];
  const float* hxs = (const float*)d_in[1];
  const float* cxs = (const float*)d_in[2];
  const float* W1  = (const float*)d_in[3];
  const float* b1  = (const float*)d_in[4];
  const float* W2  = (const float*)d_in[5];
  const float* b2  = (const float*)d_in[6];
  const float* Wih = (const float*)d_in[7];
  const float* Whh = (const float*)d_in[8];
  const float* bih = (const float*)d_in[9];
  const float* bhh = (const float*)d_in[10];
  const float* lng = (const float*)d_in[11];
  const float* lnb = (const float*)d_in[12];
  const float* Wa  = (const float*)d_in[13];
  const float* ba  = (const float*)d_in[14];
  const float* Wc  = (const float*)d_in[15];
  const float* bc  = (const float*)d_in[16];

  char* ws = (char*)d_ws;
  size_t off = 0;
  auto alloc = [&](size_t bytes) -> char* {
    char* p = ws + off;
    off += (bytes + 255) & ~(size_t)255;
    return p;
  };
  _Float16* obs16 = (_Float16*)alloc(4194304ull * 2);
  _Float16* W1x   = (_Float16*)alloc(262144ull * 2);
  _Float16* W2x   = (_Float16*)alloc(1048576ull * 2);
  _Float16* Wihx  = (_Float16*)alloc(4194304ull * 2);
  _Float16* Whhx  = (_Float16*)alloc(4194304ull * 2);
  _Float16* Wax   = (_Float16*)alloc(65536ull * 2);
  _Float16* Wcx   = (_Float16*)alloc(1024ull * 2);
  _Float16* enc1  = (_Float16*)alloc(16384ull * 1024 * 2);
  _Float16* enc2  = (_Float16*)alloc(16384ull * 1024 * 2);
  _Float16* gx    = (_Float16*)alloc(16384ull * 4096 * 2);
  _Float16* hstate= (_Float16*)alloc(2ull * 32 * 1024 * 2);
  int* flags      = (int*)alloc(64ull * 16 * 4);
  _Float16* outh  = (_Float16*)alloc(16384ull * 1024 * 2);
  float* arpart   = (float*)alloc(16384ull * 4);
  float* tarpart  = (float*)alloc(2048ull * 4);
  _Float16* normed = enc1;   // enc1 dead after G2 -> reuse for LN output

  float* out_f      = (float*)d_out;
  float* out_logits = out_f;                 // 1048576
  float* out_values = out_f + 1048576;       // 16384
  float* out_hn     = out_f + 1064960;       // 32768
  float* out_cn     = out_f + 1097728;       // 32768
  float* out_loss   = out_f + 1130496;       // 2

  // reset flags every call (replay safety)
  hipMemsetAsync(flags, 0, 64ull * 16 * 4, stream);

  // all f32->f16 conversions in one launch (h0 init = segment 7: parity 0)
  k_convert_all<<<2048, 256, 0, stream>>>(
      obs, obs16, 4194304 / 4,
      W1, W1x, 262144 / 4,
      W2, W2x, 1048576 / 4,
      Wih, Wihx, 4194304 / 4,
      Whh, Whhx, 4194304 / 4,
      Wa, Wax, 65536 / 4,
      Wc, Wcx, 1024 / 4,
      hxs, hstate, 32768 / 4);

  // encoder
  k_gemm<0><<<dim3(128, 8), 256, 0, stream>>>(obs16, W1x, enc1, b1, nullptr, 16384, 1024, 256);
  k_gemm<0><<<dim3(128, 8), 256, 0, stream>>>(enc1, W2x, enc2, b2, nullptr, 16384, 1024, 1024);
  // gx = enc2 @ W_ih^T + b_ih + b_hh
  k_gemm<1><<<dim3(128, 32), 256, 0, stream>>>(enc2, Wihx, gx, bih, bhh, 16384, 4096, 1024);
  // LSTM scan (64 persistent blocks, minimal-drain flag protocol)
  k_scan<<<64, 256, 0, stream>>>(gx, Whhx, cxs, hstate, flags, outh, out_hn, out_cn);
  // LayerNorm + losses
  k_ln<<<16384, 256, 0, stream>>>(outh, lng, lnb, normed, arpart);
  k_tar<<<2048, 256, 0, stream>>>(normed, tarpart);
  k_reduce<<<1, 256, 0, stream>>>(arpart, tarpart, out_loss);
  // heads
  k_logits<<<256, 256, 0, stream>>>(normed, Wax, ba, out_logits);
  k_values<<<256, 256, 0, stream>>>(normed, Wcx, bc, out_values);
  (void)in_sizes; (void)n_in; (void)out_size; (void)ws_size;
}

// Round 15
// 3341.752 us; speedup vs baseline: 2.1466x; 1.0005x over previous
//
#include <hip/hip_runtime.h>

// ---------------------------------------------------------------------------
// LSTMPPOPolicy: encoder(2x Linear+SiLU) -> LSTM(T=512 scan) -> LN -> heads
// B=32 T=512 OBS=256 ENC=1024 H=1024 A=64.  fp16 MFMA (f32 accum).
// FINAL = R9/R13 (best measured: 3,343us total; scan 3,002us = 5.87us/step,
// reproduced twice).  Eight scan-protocol variants bracket the floor:
//   - detect CANNOT merge into the data load (R4/R6/R12: consumer reads
//     arrive before producer stores are MALL-visible; retries congest)
//   - scope reduction to XCD-L2 (R14) fails correctness from HIP source
//   - per-step cost = poll-detect + payload RT + compute + minimal drain;
//     agent fences, full drains, extra barriers, convoy fan-in all removed.
// Scan is latency-bound (2% HBM, 1.8% MFMA): 512 serialized MALL-scope
// exchanges x ~5.9us.  Structural floor for HIP on this fabric.
// ---------------------------------------------------------------------------

typedef _Float16 half8 __attribute__((ext_vector_type(8)));
typedef _Float16 half4v __attribute__((ext_vector_type(4)));
typedef float floatx4 __attribute__((ext_vector_type(4)));
typedef unsigned long long ull;

__device__ __forceinline__ float sigmoidf_(float x) { return 1.f / (1.f + __expf(-x)); }
__device__ __forceinline__ float tanhf_(float x) {
  x = fminf(15.f, fmaxf(-15.f, x));
  float e = __expf(-2.f * x);
  return (1.f - e) / (1.f + e);
}

// ---------------- merged f32 -> f16 convert (8 segments, grid-stride) ------
__global__ __launch_bounds__(256) void k_convert_all(
    const float* s0, _Float16* d0, int n0,   // vec4 counts
    const float* s1, _Float16* d1, int n1,
    const float* s2, _Float16* d2, int n2,
    const float* s3, _Float16* d3, int n3,
    const float* s4, _Float16* d4, int n4,
    const float* s5, _Float16* d5, int n5,
    const float* s6, _Float16* d6, int n6,
    const float* s7, _Float16* d7, int n7)
{
  const int gid = blockIdx.x * 256 + threadIdx.x;
  const int stride = gridDim.x * 256;
#define CONV_SEG(s, d, n)                                                  \
  for (int i = gid; i < (n); i += stride) {                                \
    floatx4 v = *(const floatx4*)((s) + (size_t)i * 4);                    \
    half4v h;                                                              \
    h[0] = (_Float16)v[0]; h[1] = (_Float16)v[1];                          \
    h[2] = (_Float16)v[2]; h[3] = (_Float16)v[3];                          \
    *(half4v*)((d) + (size_t)i * 4) = h;                                   \
  }
  CONV_SEG(s0, d0, n0)
  CONV_SEG(s1, d1, n1)
  CONV_SEG(s2, d2, n2)
  CONV_SEG(s3, d3, n3)
  CONV_SEG(s4, d4, n4)
  CONV_SEG(s5, d5, n5)
  CONV_SEG(s6, d6, n6)
  CONV_SEG(s7, d7, n7)
#undef CONV_SEG
}

// ---------------- fp16 MFMA GEMM: C = epi(A @ B^T + bias) ------------------
template<int EPI>
__global__ __launch_bounds__(256) void k_gemm(
    const _Float16* __restrict__ A, const _Float16* __restrict__ B,
    _Float16* __restrict__ C, const float* __restrict__ bias0,
    const float* __restrict__ bias1, int M, int N, int K)
{
  __shared__ _Float16 As[128 * 32];
  __shared__ _Float16 Bs[128 * 32];
  const int tid = threadIdx.x;
  const int l = tid & 63;
  const int w = tid >> 6;
  const int wr = w >> 1, wc = w & 1;
  const _Float16* Ab = A + (size_t)blockIdx.x * 128 * K;
  const _Float16* Bb = B + (size_t)blockIdx.y * 128 * K;

  floatx4 acc[4][4];
#pragma unroll
  for (int a = 0; a < 4; ++a)
#pragma unroll
    for (int b = 0; b < 4; ++b) acc[a][b] = (floatx4){0.f, 0.f, 0.f, 0.f};

  const int ci0 = tid, ci1 = tid + 256;
  const int r0 = ci0 >> 2, r1 = ci1 >> 2;
  const int q0 = (ci0 & 3) ^ ((r0 >> 2) & 3);
  const int q1 = (ci1 & 3) ^ ((r1 >> 2) & 3);
  const int lr = l & 15;
  const int ko = l >> 4;
  const int nkt = K >> 5;

  for (int kt = 0; kt < nkt; ++kt) {
    const _Float16* Ak = Ab + kt * 32;
    const _Float16* Bk = Bb + kt * 32;
    uint4 va0 = *(const uint4*)(Ak + (size_t)r0 * K + q0 * 8);
    uint4 va1 = *(const uint4*)(Ak + (size_t)r1 * K + q1 * 8);
    uint4 vb0 = *(const uint4*)(Bk + (size_t)r0 * K + q0 * 8);
    uint4 vb1 = *(const uint4*)(Bk + (size_t)r1 * K + q1 * 8);
    __syncthreads();
    *(uint4*)(As + ci0 * 8) = va0;
    *(uint4*)(As + ci1 * 8) = va1;
    *(uint4*)(Bs + ci0 * 8) = vb0;
    *(uint4*)(Bs + ci1 * 8) = vb1;
    __syncthreads();
    half8 af[4], bf[4];
#pragma unroll
    for (int mr = 0; mr < 4; ++mr) {
      int row = wr * 64 + mr * 16 + lr;
      int cq = ko ^ ((row >> 2) & 3);
      af[mr] = *(const half8*)(As + row * 32 + cq * 8);
    }
#pragma unroll
    for (int nc = 0; nc < 4; ++nc) {
      int col = wc * 64 + nc * 16 + lr;
      int cq = ko ^ ((col >> 2) & 3);
      bf[nc] = *(const half8*)(Bs + col * 32 + cq * 8);
    }
#pragma unroll
    for (int mr = 0; mr < 4; ++mr)
#pragma unroll
      for (int nc = 0; nc < 4; ++nc)
        acc[mr][nc] = __builtin_amdgcn_mfma_f32_16x16x32_f16(af[mr], bf[nc], acc[mr][nc], 0, 0, 0);
  }

  const int lq = l >> 4;
#pragma unroll
  for (int nc = 0; nc < 4; ++nc) {
    int gcol = blockIdx.y * 128 + wc * 64 + nc * 16 + lr;
    float bia = bias0[gcol];
    if (EPI == 1) bia += bias1[gcol];
#pragma unroll
    for (int mr = 0; mr < 4; ++mr) {
      int grow = blockIdx.x * 128 + wr * 64 + mr * 16 + lq * 4;
#pragma unroll
      for (int i = 0; i < 4; ++i) {
        float v = acc[mr][nc][i] + bia;
        if (EPI == 0) v = v * sigmoidf_(v);
        C[(size_t)(grow + i) * N + gcol] = (_Float16)v;
      }
    }
  }
}

// ---------------- persistent LSTM scan (minimal drain, R9) ------------------
// 64 blocks x 256 threads.  Per step:
//   all waves poll flags>=t (64 lanes x 1 flag, s_sleep backoff)
//   32 x 8B sc1 h-loads -> MFMA (compiler counted waits)
//   red staging -> lgkmcnt(0) + raw s_barrier
//   gates -> h-store (4B sc1) -> vmcnt(0) -> raw s_barrier
//   tid0: flag=t+1   (critical path ends here)
//   background: outh store, out_hn/cn (t=511), gx prefetch t+1
__global__ __launch_bounds__(256, 1) void k_scan(
    const _Float16* __restrict__ gx,    // [32][512][4096]
    const _Float16* __restrict__ Whh,   // [4096][1024] f16
    const float* __restrict__ cxs,      // [32][1024]
    _Float16* __restrict__ hstate,      // [2][32][1024]
    int* __restrict__ flags,            // [64] x16-int padded
    _Float16* __restrict__ outh,        // [32][512][1024]
    float* __restrict__ out_hn, float* __restrict__ out_cn)
{
  const int blk = blockIdx.x;           // 0..63
  const int hbase = blk * 16;
  const int tid = threadIdx.x, l = tid & 63, wq = tid >> 6;
  __shared__ float red[4][4][2][4][65]; // [wave][gate][mtile][reg][lane+pad]

  const int cc = l & 15, ko = l >> 4;

  // B-frag preload: lane holds gate col q*1024+hbase+cc, k = wq*256+kk*32+ko*8
  half8 bfr[4][8];
#pragma unroll
  for (int q = 0; q < 4; ++q)
#pragma unroll
    for (int kk = 0; kk < 8; ++kk)
      bfr[q][kk] = *(const half8*)(Whh + (size_t)(q * 1024 + hbase + cc) * 1024
                                   + wq * 256 + kk * 32 + ko * 8);

  // gate-phase ownership: thread -> (batch gb, col pair gc2)
  const int gb = tid >> 3, gc2 = tid & 7;
  float c0 = cxs[gb * 1024 + hbase + gc2 * 2 + 0];
  float c1 = cxs[gb * 1024 + hbase + gc2 * 2 + 1];
  const int gmt = gb >> 4, greg = gb & 3;
  const int lane0 = ((gb & 15) >> 2) * 16 + gc2 * 2;

  // prologue: gx prefetch for t=0
  unsigned gxv[4];
#pragma unroll
  for (int q = 0; q < 4; ++q)
    gxv[q] = *(const unsigned*)(gx + (size_t)gb * 512 * 4096
                                + q * 1024 + hbase + gc2 * 2);

  for (int t = 0; t < 512; ++t) {
    if (t > 0) {
      // all-wave poll: lane l watches producer-block l's flag (4B sc1)
      const int* fp = flags + l * 16;
      int guard = 0;
      while (true) {
        int f = __hip_atomic_load(fp, __ATOMIC_RELAXED, __HIP_MEMORY_SCOPE_AGENT);
        if (__all(f >= t)) break;
        if (++guard > (1 << 17)) break;   // fail loud, not hang
        __builtin_amdgcn_s_sleep(1);
      }
      asm volatile("" ::: "memory");
      __builtin_amdgcn_sched_barrier(0);
    }

    // h-loads: 32 x 8B sc1 per lane; compiler inserts counted waits at use
    const _Float16* hcur = hstate + (size_t)(t & 1) * 32768;
    const ull* p0 = (const ull*)(hcur + cc * 1024 + wq * 256 + ko * 8);
    const ull* p1 = (const ull*)(hcur + (16 + cc) * 1024 + wq * 256 + ko * 8);
    ull ld0[16], ld1[16];
#pragma unroll
    for (int kk = 0; kk < 8; ++kk) {
      ld0[kk * 2 + 0] = __hip_atomic_load(p0 + kk * 8 + 0, __ATOMIC_RELAXED, __HIP_MEMORY_SCOPE_AGENT);
      ld0[kk * 2 + 1] = __hip_atomic_load(p0 + kk * 8 + 1, __ATOMIC_RELAXED, __HIP_MEMORY_SCOPE_AGENT);
      ld1[kk * 2 + 0] = __hip_atomic_load(p1 + kk * 8 + 0, __ATOMIC_RELAXED, __HIP_MEMORY_SCOPE_AGENT);
      ld1[kk * 2 + 1] = __hip_atomic_load(p1 + kk * 8 + 1, __ATOMIC_RELAXED, __HIP_MEMORY_SCOPE_AGENT);
    }

    floatx4 acc[4][2];
#pragma unroll
    for (int q = 0; q < 4; ++q) {
      acc[q][0] = (floatx4){0.f, 0.f, 0.f, 0.f};
      acc[q][1] = (floatx4){0.f, 0.f, 0.f, 0.f};
    }
#pragma unroll
    for (int kk = 0; kk < 8; ++kk) {
      union { ull u2[2]; half8 h; } a0, a1;
      a0.u2[0] = ld0[kk * 2 + 0]; a0.u2[1] = ld0[kk * 2 + 1];
      a1.u2[0] = ld1[kk * 2 + 0]; a1.u2[1] = ld1[kk * 2 + 1];
#pragma unroll
      for (int q = 0; q < 4; ++q) {
        acc[q][0] = __builtin_amdgcn_mfma_f32_16x16x32_f16(a0.h, bfr[q][kk], acc[q][0], 0, 0, 0);
        acc[q][1] = __builtin_amdgcn_mfma_f32_16x16x32_f16(a1.h, bfr[q][kk], acc[q][1], 0, 0, 0);
      }
    }
    // transposed reduce staging
#pragma unroll
    for (int q = 0; q < 4; ++q)
#pragma unroll
      for (int mt = 0; mt < 2; ++mt)
#pragma unroll
        for (int i = 0; i < 4; ++i)
          red[wq][q][mt][i][l] = acc[q][mt][i];
    asm volatile("s_waitcnt lgkmcnt(0)" ::: "memory");   // LDS writes done
    __builtin_amdgcn_s_barrier();                         // raw barrier
    __builtin_amdgcn_sched_barrier(0);

    // gate phase: all 256 threads, (batch gb, cols 2gc2, 2gc2+1)
    float pre0[4], pre1[4];
#pragma unroll
    for (int q = 0; q < 4; ++q) {
      pre0[q] = red[0][q][gmt][greg][lane0] + red[1][q][gmt][greg][lane0]
              + red[2][q][gmt][greg][lane0] + red[3][q][gmt][greg][lane0];
      pre1[q] = red[0][q][gmt][greg][lane0 + 1] + red[1][q][gmt][greg][lane0 + 1]
              + red[2][q][gmt][greg][lane0 + 1] + red[3][q][gmt][greg][lane0 + 1];
    }
    union { unsigned u; _Float16 h[2]; } g0, g1, g2, g3;
    g0.u = gxv[0]; g1.u = gxv[1]; g2.u = gxv[2]; g3.u = gxv[3];

    float i0 = sigmoidf_(pre0[0] + (float)g0.h[0]);
    float f0 = sigmoidf_(pre0[1] + (float)g1.h[0]);
    float gg0 = tanhf_(pre0[2] + (float)g2.h[0]);
    float o0 = sigmoidf_(pre0[3] + (float)g3.h[0]);
    c0 = f0 * c0 + i0 * gg0;
    float h0 = o0 * tanhf_(c0);

    float i1 = sigmoidf_(pre1[0] + (float)g0.h[1]);
    float f1 = sigmoidf_(pre1[1] + (float)g1.h[1]);
    float gg1 = tanhf_(pre1[2] + (float)g2.h[1]);
    float o1 = sigmoidf_(pre1[3] + (float)g3.h[1]);
    c1 = f1 * c1 + i1 * gg1;
    float h1 = o1 * tanhf_(c1);

    union { _Float16 h[2]; unsigned u; } hp;
    hp.h[0] = (_Float16)h0; hp.h[1] = (_Float16)h1;

    // CRITICAL PATH TAIL: h-store (4B sc1) -> drain it -> barrier -> flag
    __hip_atomic_store((unsigned*)(hstate + (size_t)((t + 1) & 1) * 32768
                                   + (size_t)gb * 1024 + hbase + gc2 * 2),
                       hp.u, __ATOMIC_RELAXED, __HIP_MEMORY_SCOPE_AGENT);
    asm volatile("s_waitcnt vmcnt(0)" ::: "memory");  // h-store ack only
    __builtin_amdgcn_sched_barrier(0);
    __builtin_amdgcn_s_barrier();                     // all 4 waves drained
    if (tid == 0 && t < 511)
      __hip_atomic_store(flags + blk * 16, t + 1, __ATOMIC_RELAXED,
                         __HIP_MEMORY_SCOPE_AGENT);

    // BACKGROUND (latency absorbed by next step's poll window):
    *(unsigned*)(outh + ((size_t)gb * 512 + t) * 1024 + hbase + gc2 * 2) = hp.u;
    if (t == 511) {
      float2 hv; hv.x = h0; hv.y = h1;
      float2 cv; cv.x = c0; cv.y = c1;
      *(float2*)(out_hn + gb * 1024 + hbase + gc2 * 2) = hv;
      *(float2*)(out_cn + gb * 1024 + hbase + gc2 * 2) = cv;
    } else {
#pragma unroll
      for (int q = 0; q < 4; ++q)
        gxv[q] = *(const unsigned*)(gx + ((size_t)gb * 512 + t + 1) * 4096
                                    + q * 1024 + hbase + gc2 * 2);
    }
    __builtin_amdgcn_sched_barrier(0);  // pin background issue before backedge
  }
}

// ---------------- LayerNorm (per row of 1024) + ar partial ------------------
__global__ __launch_bounds__(256) void k_ln(
    const _Float16* __restrict__ x, const float* __restrict__ gam,
    const float* __restrict__ bet, _Float16* __restrict__ y,
    float* __restrict__ arpart)
{
  const int m = blockIdx.x;
  const int tid = threadIdx.x;
  const int w = tid >> 6, l = tid & 63;
  half4v v = *(const half4v*)(x + (size_t)m * 1024 + tid * 4);
  float xv[4]; float s = 0.f, ss = 0.f;
#pragma unroll
  for (int j = 0; j < 4; ++j) { xv[j] = (float)v[j]; s += xv[j]; ss += xv[j] * xv[j]; }
#pragma unroll
  for (int off = 32; off > 0; off >>= 1) { s += __shfl_xor(s, off, 64); ss += __shfl_xor(ss, off, 64); }
  __shared__ float sw[4], ssw[4], bcast[2];
  if (l == 0) { sw[w] = s; ssw[w] = ss; }
  __syncthreads();
  if (tid == 0) {
    float S = sw[0] + sw[1] + sw[2] + sw[3];
    float SS = ssw[0] + ssw[1] + ssw[2] + ssw[3];
    float mu = S * (1.f / 1024.f);
    float var = SS * (1.f / 1024.f) - mu * mu;
    bcast[0] = mu; bcast[1] = rsqrtf(var + 1e-5f);
  }
  __syncthreads();
  float mu = bcast[0], rstd = bcast[1];
  float part = 0.f; half4v o;
#pragma unroll
  for (int j = 0; j < 4; ++j) {
    float nv = (xv[j] - mu) * rstd * gam[tid * 4 + j] + bet[tid * 4 + j];
    o[j] = (_Float16)nv;
    part += nv * nv;
  }
  *(half4v*)(y + (size_t)m * 1024 + tid * 4) = o;
#pragma unroll
  for (int off = 32; off > 0; off >>= 1) part += __shfl_xor(part, off, 64);
  if (l == 0) sw[w] = part;
  __syncthreads();
  if (tid == 0) arpart[m] = sw[0] + sw[1] + sw[2] + sw[3];
}

// ---------------- temporal-diff loss partials -------------------------------
__global__ __launch_bounds__(256) void k_tar(const _Float16* __restrict__ y, float* __restrict__ tarpart) {
  const int tid = threadIdx.x;
  int gid = blockIdx.x * 256 + tid;
  const int stride = gridDim.x * 256;
  const int TOT = 32 * 511 * 256;  // vec4 groups
  float s = 0.f;
  for (int v = gid; v < TOT; v += stride) {
    int b = v / (511 * 256);
    int r = v - b * (511 * 256);
    size_t base = (size_t)b * 512 * 1024 + (size_t)r * 4;
    half4v a = *(const half4v*)(y + base);
    half4v c = *(const half4v*)(y + base + 1024);
#pragma unroll
    for (int j = 0; j < 4; ++j) { float d = (float)c[j] - (float)a[j]; s += d * d; }
  }
#pragma unroll
  for (int off = 32; off > 0; off >>= 1) s += __shfl_xor(s, off, 64);
  __shared__ float sw[4];
  if ((tid & 63) == 0) sw[tid >> 6] = s;
  __syncthreads();
  if (tid == 0) tarpart[blockIdx.x] = sw[0] + sw[1] + sw[2] + sw[3];
}

__global__ __launch_bounds__(256) void k_reduce(
    const float* __restrict__ arpart, const float* __restrict__ tarpart,
    float* __restrict__ dst)
{
  const int tid = threadIdx.x;
  float a = 0.f, t = 0.f;
  for (int i = tid; i < 16384; i += 256) a += arpart[i];
  for (int i = tid; i < 2048; i += 256) t += tarpart[i];
#pragma unroll
  for (int off = 32; off > 0; off >>= 1) { a += __shfl_xor(a, off, 64); t += __shfl_xor(t, off, 64); }
  __shared__ float sa[4], st[4];
  if ((tid & 63) == 0) { sa[tid >> 6] = a; st[tid >> 6] = t; }
  __syncthreads();
  if (tid == 0) {
    dst[0] = (sa[0] + sa[1] + sa[2] + sa[3]) * (0.01f / 16777216.f);
    dst[1] = (st[0] + st[1] + st[2] + st[3]) * (0.01f / 16744448.f);
  }
}

// ---------------- logits head: [16384,1024] @ [64,1024]^T + ba --------------
__global__ __launch_bounds__(256) void k_logits(
    const _Float16* __restrict__ X, const _Float16* __restrict__ Wa,
    const float* __restrict__ ba, float* __restrict__ out)
{
  const int tid = threadIdx.x, l = tid & 63, w = tid >> 6;
  const int lr = l & 15, lq = l >> 4;
  const int rowb = blockIdx.x * 64 + w * 16;
  floatx4 acc[4];
#pragma unroll
  for (int nc = 0; nc < 4; ++nc) acc[nc] = (floatx4){0.f, 0.f, 0.f, 0.f};
  for (int kc = 0; kc < 32; ++kc) {
    int k = kc * 32 + lq * 8;
    half8 af = *(const half8*)(X + (size_t)(rowb + lr) * 1024 + k);
#pragma unroll
    for (int nc = 0; nc < 4; ++nc) {
      half8 bf = *(const half8*)(Wa + (size_t)(nc * 16 + lr) * 1024 + k);
      acc[nc] = __builtin_amdgcn_mfma_f32_16x16x32_f16(af, bf, acc[nc], 0, 0, 0);
    }
  }
#pragma unroll
  for (int nc = 0; nc < 4; ++nc) {
    int col = nc * 16 + lr;
    float bia = ba[col];
#pragma unroll
    for (int i = 0; i < 4; ++i) {
      int grow = rowb + lq * 4 + i;
      out[(size_t)grow * 64 + col] = acc[nc][i] + bia;
    }
  }
}

// ---------------- value head: dot(row, Wc) + bc -----------------------------
__global__ __launch_bounds__(256) void k_values(
    const _Float16* __restrict__ X, const _Float16* __restrict__ Wc,
    const float* __restrict__ bc, float* __restrict__ out)
{
  const int tid = threadIdx.x, l = tid & 63, w = tid >> 6;
  half8 w0 = *(const half8*)(Wc + l * 16);
  half8 w1 = *(const half8*)(Wc + l * 16 + 8);
  float bias = bc[0];
  const int rowb = blockIdx.x * 64 + w * 16;
  for (int r = 0; r < 16; ++r) {
    const _Float16* xr = X + (size_t)(rowb + r) * 1024 + l * 16;
    half8 x0 = *(const half8*)(xr);
    half8 x1 = *(const half8*)(xr + 8);
    float s = 0.f;
#pragma unroll
    for (int j = 0; j < 8; ++j) s += (float)x0[j] * (float)w0[j] + (float)x1[j] * (float)w1[j];
#pragma unroll
    for (int off = 32; off > 0; off >>= 1) s += __shfl_xor(s, off, 64);
    if (l == 0) out[rowb + r] = s + bias;
  }
}

// ---------------------------------------------------------------------------
extern "C" void kernel_launch(void* const* d_in, const int* in_sizes, int n_in,
                              void* d_out, int out_size, void* d_ws, size_t ws_size,
                              hipStream_t stream)
{
  const float* obs = (const float*)d_in[0];
  const float* hxs = (const float*)d_in[1];
  const float* cxs = (const float*)d_in[2];
  const float* W1  = (const float*)d_in[3];
  const float* b1  = (const float*)d_in[4];
  const float* W2  = (const float*)d_in[5];
  const float* b2  = (const float*)d_in[6];
  const float* Wih = (const float*)d_in[7];
  const float* Whh = (const float*)d_in[8];
  const float* bih = (const float*)d_in[9];
  const float* bhh = (const float*)d_in[10];
  const float* lng = (const float*)d_in[11];
  const float* lnb = (const float*)d_in[12];
  const float* Wa  = (const float*)d_in[13];
  const float* ba  = (const float*)d_in[14];
  const float* Wc  = (const float*)d_in[15];
  const float* bc  = (const float*)d_in[16];

  char* ws = (char*)d_ws;
  size_t off = 0;
  auto alloc = [&](size_t bytes) -> char* {
    char* p = ws + off;
    off += (bytes + 255) & ~(size_t)255;
    return p;
  };
  _Float16* obs16 = (_Float16*)alloc(4194304ull * 2);
  _Float16* W1x   = (_Float16*)alloc(262144ull * 2);
  _Float16* W2x   = (_Float16*)alloc(1048576ull * 2);
  _Float16* Wihx  = (_Float16*)alloc(4194304ull * 2);
  _Float16* Whhx  = (_Float16*)alloc(4194304ull * 2);
  _Float16* Wax   = (_Float16*)alloc(65536ull * 2);
  _Float16* Wcx   = (_Float16*)alloc(1024ull * 2);
  _Float16* enc1  = (_Float16*)alloc(16384ull * 1024 * 2);
  _Float16* enc2  = (_Float16*)alloc(16384ull * 1024 * 2);
  _Float16* gx    = (_Float16*)alloc(16384ull * 4096 * 2);
  _Float16* hstate= (_Float16*)alloc(2ull * 32 * 1024 * 2);
  int* flags      = (int*)alloc(64ull * 16 * 4);
  _Float16* outh  = (_Float16*)alloc(16384ull * 1024 * 2);
  float* arpart   = (float*)alloc(16384ull * 4);
  float* tarpart  = (float*)alloc(2048ull * 4);
  _Float16* normed = enc1;   // enc1 dead after G2 -> reuse for LN output

  float* out_f      = (float*)d_out;
  float* out_logits = out_f;                 // 1048576
  float* out_values = out_f + 1048576;       // 16384
  float* out_hn     = out_f + 1064960;       // 32768
  float* out_cn     = out_f + 1097728;       // 32768
  float* out_loss   = out_f + 1130496;       // 2

  // reset flags every call (replay safety)
  hipMemsetAsync(flags, 0, 64ull * 16 * 4, stream);

  // all f32->f16 conversions in one launch (h0 init = segment 7: parity 0)
  k_convert_all<<<2048, 256, 0, stream>>>(
      obs, obs16, 4194304 / 4,
      W1, W1x, 262144 / 4,
      W2, W2x, 1048576 / 4,
      Wih, Wihx, 4194304 / 4,
      Whh, Whhx, 4194304 / 4,
      Wa, Wax, 65536 / 4,
      Wc, Wcx, 1024 / 4,
      hxs, hstate, 32768 / 4);

  // encoder
  k_gemm<0><<<dim3(128, 8), 256, 0, stream>>>(obs16, W1x, enc1, b1, nullptr, 16384, 1024, 256);
  k_gemm<0><<<dim3(128, 8), 256, 0, stream>>>(enc1, W2x, enc2, b2, nullptr, 16384, 1024, 1024);
  // gx = enc2 @ W_ih^T + b_ih + b_hh
  k_gemm<1><<<dim3(128, 32), 256, 0, stream>>>(enc2, Wihx, gx, bih, bhh, 16384, 4096, 1024);
  // LSTM scan (64 persistent blocks, minimal-drain flag protocol)
  k_scan<<<64, 256, 0, stream>>>(gx, Whhx, cxs, hstate, flags, outh, out_hn, out_cn);
  // LayerNorm + losses
  k_ln<<<16384, 256, 0, stream>>>(outh, lng, lnb, normed, arpart);
  k_tar<<<2048, 256, 0, stream>>>(normed, tarpart);
  k_reduce<<<1, 256, 0, stream>>>(arpart, tarpart, out_loss);
  // heads
  k_logits<<<256, 256, 0, stream>>>(normed, Wax, ba, out_logits);
  k_values<<<256, 256, 0, stream>>>(normed, Wcx, bc, out_values);
  (void)in_sizes; (void)n_in; (void)out_size; (void)ws_size;
}